// Round 2
// baseline (696.173 us; speedup 1.0000x reference)
//
#include <hip/hip_runtime.h>
#include <math.h>

#define LEN   2048
#define EDIM  512
#define NB    16
#define NH    8
#define HD    64
#define TOPK  7

__device__ inline float2 cmul(float2 a, float2 b) {
    return make_float2(a.x * b.x - a.y * b.y, a.x * b.y + a.y * b.x);
}

// K0: (B, L, E) -> (B*E, L) transpose for q and k. 32x32 tiles.
__global__ __launch_bounds__(256) void transpose_qk(const float* __restrict__ q,
                                                    const float* __restrict__ k,
                                                    float* __restrict__ qT,
                                                    float* __restrict__ kT) {
    __shared__ float tile[32][33];
    int b  = blockIdx.z;
    int e0 = blockIdx.x * 32;
    int t0 = blockIdx.y * 32;
    const float* qb = q + (size_t)b * LEN * EDIM;
    const float* kb = k + (size_t)b * LEN * EDIM;
    float* qTb = qT + (size_t)b * EDIM * LEN;
    float* kTb = kT + (size_t)b * EDIM * LEN;
    int x = threadIdx.x;   // 0..31
    int y = threadIdx.y;   // 0..7
    for (int r = 0; r < 32; r += 8)
        tile[y + r][x] = qb[(size_t)(t0 + y + r) * EDIM + e0 + x];
    __syncthreads();
    for (int r = 0; r < 32; r += 8)
        qTb[(size_t)(e0 + y + r) * LEN + t0 + x] = tile[x][y + r];
    __syncthreads();
    for (int r = 0; r < 32; r += 8)
        tile[y + r][x] = kb[(size_t)(t0 + y + r) * EDIM + e0 + x];
    __syncthreads();
    for (int r = 0; r < 32; r += 8)
        kTb[(size_t)(e0 + y + r) * LEN + t0 + x] = tile[x][y + r];
}

// FFT core: radix-2, DIF forward (natural->bitrev), pointwise Q*conj(K) in
// bitrev domain, DIT inverse (bitrev->natural). A, Bs, TW in LDS.
__device__ inline void fft_corr_core(float2* A, float2* Bs, float2* TW, int tid) {
    for (int s = 0; s < 11; ++s) {
        int m = 1024 >> s;
        for (int j = tid; j < 1024; j += 256) {
            int t  = j & (m - 1);
            int i0 = ((j >> (10 - s)) << (11 - s)) + t;
            int i1 = i0 + m;
            float2 w = TW[t << s];
            float2 a = A[i0], b = A[i1];
            A[i0] = make_float2(a.x + b.x, a.y + b.y);
            A[i1] = cmul(make_float2(a.x - b.x, a.y - b.y), w);
            a = Bs[i0]; b = Bs[i1];
            Bs[i0] = make_float2(a.x + b.x, a.y + b.y);
            Bs[i1] = cmul(make_float2(a.x - b.x, a.y - b.y), w);
        }
        __syncthreads();
    }
    for (int t = tid; t < LEN; t += 256) {
        float2 a = A[t], b = Bs[t];
        A[t] = make_float2(a.x * b.x + a.y * b.y, a.y * b.x - a.x * b.y);
    }
    __syncthreads();
    for (int s = 0; s < 11; ++s) {
        int m = 1 << s;
        for (int j = tid; j < 1024; j += 256) {
            int t  = j & (m - 1);
            int i0 = ((j >> s) << (s + 1)) + t;
            int i1 = i0 + m;
            float2 wc = TW[t << (10 - s)];
            float2 w  = make_float2(wc.x, -wc.y);   // conj for inverse
            float2 a  = A[i0];
            float2 b  = cmul(A[i1], w);
            A[i0] = make_float2(a.x + b.x, a.y + b.y);
            A[i1] = make_float2(a.x - b.x, a.y - b.y);
        }
        __syncthreads();
    }
}

// K1 (Path A): contiguous rows (from transposed buffers).
// corr may alias qT (each block reads its full row into LDS before writing).
__global__ __launch_bounds__(256) void fft_corr(const float* qT,
                                                const float* kT,
                                                float* corr) {
    __shared__ float2 A[LEN];
    __shared__ float2 Bs[LEN];
    __shared__ float2 TW[LEN / 2];
    int ch  = blockIdx.x;
    int tid = threadIdx.x;
    const float* qr = qT + (size_t)ch * LEN;
    const float* kr = kT + (size_t)ch * LEN;
    for (int j = tid; j < LEN / 2; j += 256) {
        float s, c;
        sincosf(-6.283185307179586f * (float)j / (float)LEN, &s, &c);
        TW[j] = make_float2(c, s);
    }
    for (int t = tid; t < LEN; t += 256) {
        A[t]  = make_float2(qr[t], 0.f);
        Bs[t] = make_float2(kr[t], 0.f);
    }
    __syncthreads();
    fft_corr_core(A, Bs, TW, tid);
    const float inv = 1.0f / (float)LEN;
    for (int t = tid; t < LEN; t += 256)
        corr[(size_t)ch * LEN + t] = A[t].x * inv;
}

// K1 (Path B): read q,k strided directly from (B,L,E); corr rows local to chunk.
__global__ __launch_bounds__(256) void fft_corr_strided(const float* q,
                                                        const float* k,
                                                        float* corr,
                                                        int chStart) {
    __shared__ float2 A[LEN];
    __shared__ float2 Bs[LEN];
    __shared__ float2 TW[LEN / 2];
    int chLocal = blockIdx.x;
    int gch = chStart + chLocal;
    int b   = gch >> 9;           // / EDIM
    int e   = gch & (EDIM - 1);
    int tid = threadIdx.x;
    const float* qr = q + (size_t)b * LEN * EDIM + e;
    const float* kr = k + (size_t)b * LEN * EDIM + e;
    for (int j = tid; j < LEN / 2; j += 256) {
        float s, c;
        sincosf(-6.283185307179586f * (float)j / (float)LEN, &s, &c);
        TW[j] = make_float2(c, s);
    }
    for (int t = tid; t < LEN; t += 256) {
        A[t]  = make_float2(qr[(size_t)t * EDIM], 0.f);
        Bs[t] = make_float2(kr[(size_t)t * EDIM], 0.f);
    }
    __syncthreads();
    fft_corr_core(A, Bs, TW, tid);
    const float inv = 1.0f / (float)LEN;
    for (int t = tid; t < LEN; t += 256)
        corr[(size_t)chLocal * LEN + t] = A[t].x * inv;
}

// K2: per (b,h,l): top-7 over 64 channel-scores, softmax, gather-weighted sum.
// Block = 256 threads (4 waves), one (b,h), 64 consecutive l.
// corr rows are indexed relative to bhBase (chunk-local).
__global__ __launch_bounds__(256) void topk_agg(const float* __restrict__ corr,
                                                const float* __restrict__ values,
                                                float* __restrict__ out,
                                                int bhBase) {
    __shared__ float ctile[64][65];
    int l0 = blockIdx.x * 64;
    int lh = blockIdx.y;            // local head index within chunk
    int bh = bhBase + lh;
    int b  = bh >> 3;
    int h  = bh & 7;
    int tid = threadIdx.x;

    for (int idx = tid; idx < 64 * 64; idx += 256) {
        int c  = idx >> 6;
        int lp = idx & 63;
        ctile[c][lp] = corr[((size_t)lh * 64 + c) * LEN + l0 + lp];
    }
    __syncthreads();

    int lane = tid & 63;
    int wave = tid >> 6;
    const float* vb = values + (size_t)b * LEN * EDIM + h * HD;
    float*       ob = out    + (size_t)b * LEN * EDIM + h * HD;

    for (int i = 0; i < 16; ++i) {
        int lp = wave * 16 + i;
        int l  = l0 + lp;
        float cur = ctile[lane][lp];    // lane = channel index
        float wk[TOPK];
        int   dk[TOPK];
        for (int k = 0; k < TOPK; ++k) {
            float rv = cur;
            int   rc = lane;
            for (int off = 32; off >= 1; off >>= 1) {
                float ov = __shfl_xor(rv, off, 64);
                int   oc = __shfl_xor(rc, off, 64);
                if (ov > rv || (ov == rv && oc < rc)) { rv = ov; rc = oc; }
            }
            wk[k] = rv;
            dk[k] = rc;
            if (lane == rc) cur = -INFINITY;
        }
        float mx  = wk[0];
        float sum = 0.f;
        float e[TOPK];
        for (int k = 0; k < TOPK; ++k) { e[k] = expf(wk[k] - mx); sum += e[k]; }
        float invs = 1.f / sum;
        float acc = 0.f;
        for (int k = 0; k < TOPK; ++k) {
            int idx = (l - dk[k]) & (LEN - 1);
            acc += e[k] * invs * vb[(size_t)idx * EDIM + lane];
        }
        ob[(size_t)l * EDIM + lane] = acc;
    }
}

extern "C" void kernel_launch(void* const* d_in, const int* in_sizes, int n_in,
                              void* d_out, int out_size, void* d_ws, size_t ws_size,
                              hipStream_t stream) {
    const float* q = (const float*)d_in[0];
    const float* k = (const float*)d_in[1];
    const float* v = (const float*)d_in[2];
    float* out = (float*)d_out;

    const size_t CORR_BYTES = (size_t)NB * EDIM * LEN * sizeof(float);  // 64 MB

    if (ws_size >= CORR_BYTES) {
        // Path A: qT in ws; kT staged in d_out (dead until topk rewrites it);
        // corr aliases qT.
        float* qT   = (float*)d_ws;
        float* kT   = (float*)d_out;
        float* corr = qT;
        transpose_qk<<<dim3(EDIM / 32, LEN / 32, NB), dim3(32, 8), 0, stream>>>(q, k, qT, kT);
        fft_corr<<<dim3(NB * EDIM), dim3(256), 0, stream>>>(qT, kT, corr);
        topk_agg<<<dim3(LEN / 64, NB * NH), dim3(256), 0, stream>>>(corr, v, out, 0);
    } else {
        // Path B: chunk by heads; corr chunk lives in ws (512 KB per head).
        const size_t HEAD_BYTES = (size_t)HD * LEN * sizeof(float);
        int headsPer = (int)(ws_size / HEAD_BYTES);
        if (headsPer < 1) headsPer = 1;
        if (headsPer > NB * NH) headsPer = NB * NH;
        float* corr = (float*)d_ws;
        for (int hs = 0; hs < NB * NH; hs += headsPer) {
            int hc = NB * NH - hs < headsPer ? NB * NH - hs : headsPer;
            fft_corr_strided<<<dim3(hc * HD), dim3(256), 0, stream>>>(q, k, corr, hs * HD);
            topk_agg<<<dim3(LEN / 64, hc), dim3(256), 0, stream>>>(corr, v, out, hs);
        }
    }
}